// Round 8
// baseline (835.998 us; speedup 1.0000x reference)
//
#include <hip/hip_runtime.h>

#define N_NODES 250000
#define N_EDGES 4000000
#define N_GRAPHS 512
#define NEG 0.01f
#define BINB 9
#define WIN 512
#define NBINS 489            // ceil(250000 / 512)
#define NSUB (NBINS * 4)     // dst-bin x src-quarter
#define CAPQ 2560            // per-sub-bin capacity: mean ~2147 + 9 sigma
#define PART_EPB 16384
#define PART_BLOCKS 245      // 245 * 16384 >= N_EDGES
#define INVW 0xFFFFFFFFu

__device__ __forceinline__ float lrelu(float v) { return v > 0.0f ? v : NEG * v; }
// bf16 pack (RNE) / unpack helpers, bit-level
__device__ __forceinline__ unsigned f2b(float f) {
    unsigned u = __float_as_uint(f);
    unsigned r = ((u >> 16) & 1u) + 0x7FFFu;
    return (u + r) >> 16;
}
__device__ __forceinline__ unsigned pk(float a, float b) { return f2b(a) | (f2b(b) << 16); }
__device__ __forceinline__ float blo(unsigned p) { return __uint_as_float(p << 16); }
__device__ __forceinline__ float bhi(unsigned p) { return __uint_as_float(p & 0xFFFF0000u); }

// ---- Pack x (13 f32) into x16b (16 bf16 = 32 B rows) -------------------
__global__ void pack_x(const float* __restrict__ x, unsigned* __restrict__ x16b) {
    int tid = blockIdx.x * blockDim.x + threadIdx.x;
    if (tid >= N_NODES * 8) return;
    int n = tid >> 3, d2 = tid & 7;
    int a = d2 * 2, b = a + 1;
    float va = (a < 13) ? x[n * 13 + a] : 0.0f;
    float vb = (b < 13) ? x[n * 13 + b] : 0.0f;
    x16b[tid] = pk(va, vb);
}

// ---- Edge binning into (dst-bin x src-quarter), 2-pass per block -------
__global__ void partition_k(const int* __restrict__ src, const int* __restrict__ dst,
                            int* __restrict__ qcnt, unsigned* __restrict__ binned) {
    __shared__ int hist[NSUB];   // pass1: counts; pass2: relative cursor
    __shared__ int base[NSUB];
    int t = threadIdx.x;
    for (int i = t; i < NSUB; i += 256) hist[i] = 0;
    __syncthreads();
    unsigned e0 = blockIdx.x * PART_EPB;
    // pass 1: histogram
    for (int i = 0; i < PART_EPB / 256; i++) {
        unsigned e = e0 + (unsigned)i * 256u + t;
        if (e < N_EDGES) {
            int s = ((dst[e] >> BINB) << 2) | (src[e] >> 16);
            atomicAdd(&hist[s], 1);
        }
    }
    __syncthreads();
    // reserve chunks, zero cursors
    for (int i = t; i < NSUB; i += 256) {
        int h = hist[i];
        base[i] = (h > 0) ? atomicAdd(&qcnt[i], h) : 0;
        hist[i] = 0;
    }
    __syncthreads();
    // pass 2: place
    for (int i = 0; i < PART_EPB / 256; i++) {
        unsigned e = e0 + (unsigned)i * 256u + t;
        if (e < N_EDGES) {
            int d = dst[e], sv = src[e];
            int s = ((d >> BINB) << 2) | (sv >> 16);
            int pos = base[s] + atomicAdd(&hist[s], 1);
            binned[(size_t)s * CAPQ + pos] =
                ((unsigned)(d & (WIN - 1)) << 18) | (unsigned)sv;
        }
    }
}

// ---- Layer-1 aggregation: 2 lanes/edge, 16 B bf16, src-quarter phases --
__global__ __launch_bounds__(1024) void agg13_k(const unsigned* __restrict__ x16b,
                                                const unsigned* __restrict__ binned,
                                                const int* __restrict__ qcnt,
                                                float* __restrict__ agg,
                                                float* __restrict__ cntf) {
    __shared__ float acc[WIN * 14];  // 28 KB
    int t = threadIdx.x;
    for (int i = t; i < WIN * 14; i += 1024) acc[i] = 0.0f;
    __syncthreads();
    int bin = blockIdx.x;
    int g = t >> 1, l = t & 1;   // 512 edge-slots; lane l covers dims l*8..
    const int S = 512;
    constexpr int P = 4;
    for (int q = 0; q < 4; q++) {
        int sub = (bin << 2) | q;
        int cnt = qcnt[sub];
        const unsigned* bp = binned + (size_t)sub * CAPQ;
        for (int k0 = g; k0 < cnt; k0 += P * S) {
            unsigned w[P];
            uint4 v[P];
#pragma unroll
            for (int p = 0; p < P; p++) {
                int k = k0 + p * S;
                w[p] = (k < cnt) ? bp[k] : INVW;
            }
#pragma unroll
            for (int p = 0; p < P; p++) {
                unsigned s = min(w[p] & 0x3FFFFu, (unsigned)(N_NODES - 1));
                v[p] = *(const uint4*)&x16b[(size_t)s * 8u + (unsigned)(l * 4)];
            }
#pragma unroll
            for (int p = 0; p < P; p++) {
                if (w[p] != INVW) {
                    unsigned f = w[p] >> 18;
                    float* a = &acc[f * 14u + (unsigned)(l * 8)];
                    atomicAdd(a + 0, blo(v[p].x)); atomicAdd(a + 1, bhi(v[p].x));
                    atomicAdd(a + 2, blo(v[p].y)); atomicAdd(a + 3, bhi(v[p].y));
                    atomicAdd(a + 4, blo(v[p].z));
                    if (l == 0) {
                        atomicAdd(a + 5, bhi(v[p].z));
                        atomicAdd(a + 6, blo(v[p].w)); atomicAdd(a + 7, bhi(v[p].w));
                    } else {
                        atomicAdd(a + 5, 1.0f);  // degree in col 13
                    }
                }
            }
        }
    }
    __syncthreads();
    int n0 = bin << BINB;
    int nodes = min(WIN, N_NODES - n0);
    for (int idx = t; idx < nodes * 13; idx += 1024) {
        int r = idx / 13, c = idx - r * 13;
        agg[(size_t)n0 * 13u + idx] = acc[r * 14 + c];
    }
    for (int r = t; r < nodes; r += 1024) cntf[n0 + r] = acc[r * 14 + 13];
}

// ---- Layer-2 aggregation: 1 lane/edge, 16 B bf16, phased ---------------
__global__ __launch_bounds__(1024) void agg8_k(const unsigned* __restrict__ y2b,
                                               const unsigned* __restrict__ binned,
                                               const int* __restrict__ qcnt,
                                               float* __restrict__ agg) {
    __shared__ float acc[WIN * 8];
    int t = threadIdx.x;
    for (int i = t; i < WIN * 8; i += 1024) acc[i] = 0.0f;
    __syncthreads();
    int bin = blockIdx.x;
    constexpr int P = 4;
    for (int q = 0; q < 4; q++) {
        int sub = (bin << 2) | q;
        int cnt = qcnt[sub];
        const unsigned* bp = binned + (size_t)sub * CAPQ;
        for (int k0 = t; k0 < cnt; k0 += P * 1024) {
            unsigned w[P];
            uint4 v[P];
#pragma unroll
            for (int p = 0; p < P; p++) {
                int k = k0 + p * 1024;
                w[p] = (k < cnt) ? bp[k] : INVW;
            }
#pragma unroll
            for (int p = 0; p < P; p++) {
                unsigned s = min(w[p] & 0x3FFFFu, (unsigned)(N_NODES - 1));
                v[p] = *(const uint4*)&y2b[(size_t)s * 4u];
            }
#pragma unroll
            for (int p = 0; p < P; p++) {
                if (w[p] != INVW) {
                    unsigned f = w[p] >> 18;
                    float* a = &acc[f * 8u];
                    atomicAdd(a + 0, blo(v[p].x)); atomicAdd(a + 1, bhi(v[p].x));
                    atomicAdd(a + 2, blo(v[p].y)); atomicAdd(a + 3, bhi(v[p].y));
                    atomicAdd(a + 4, blo(v[p].z)); atomicAdd(a + 5, bhi(v[p].z));
                    atomicAdd(a + 6, blo(v[p].w)); atomicAdd(a + 7, bhi(v[p].w));
                }
            }
        }
    }
    __syncthreads();
    int n0 = bin << BINB;
    int nodes = min(WIN, N_NODES - n0);
    for (int idx = t; idx < nodes * 8; idx += 1024)
        agg[(size_t)n0 * 8u + idx] = acc[idx];
}

// ---- Layer-3 aggregation: 1 lane/edge, 8 B bf16, phased ----------------
__global__ __launch_bounds__(1024) void agg4_k(const unsigned* __restrict__ y3b,
                                               const unsigned* __restrict__ binned,
                                               const int* __restrict__ qcnt,
                                               float* __restrict__ agg) {
    __shared__ float acc[WIN * 4];
    int t = threadIdx.x;
    for (int i = t; i < WIN * 4; i += 1024) acc[i] = 0.0f;
    __syncthreads();
    int bin = blockIdx.x;
    constexpr int P = 4;
    for (int q = 0; q < 4; q++) {
        int sub = (bin << 2) | q;
        int cnt = qcnt[sub];
        const unsigned* bp = binned + (size_t)sub * CAPQ;
        for (int k0 = t; k0 < cnt; k0 += P * 1024) {
            unsigned w[P];
            uint2 v[P];
#pragma unroll
            for (int p = 0; p < P; p++) {
                int k = k0 + p * 1024;
                w[p] = (k < cnt) ? bp[k] : INVW;
            }
#pragma unroll
            for (int p = 0; p < P; p++) {
                unsigned s = min(w[p] & 0x3FFFFu, (unsigned)(N_NODES - 1));
                v[p] = *(const uint2*)&y3b[(size_t)s * 2u];
            }
#pragma unroll
            for (int p = 0; p < P; p++) {
                if (w[p] != INVW) {
                    unsigned f = w[p] >> 18;
                    float* a = &acc[f * 4u];
                    atomicAdd(a + 0, blo(v[p].x)); atomicAdd(a + 1, bhi(v[p].x));
                    atomicAdd(a + 2, blo(v[p].y)); atomicAdd(a + 3, bhi(v[p].y));
                }
            }
        }
    }
    __syncthreads();
    int n0 = bin << BINB;
    int nodes = min(WIN, N_NODES - n0);
    for (int idx = t; idx < nodes * 4; idx += 1024)
        agg[(size_t)n0 * 4u + idx] = acc[idx];
}

// ---- Node-side fused linears -------------------------------------------

// h1 = lrelu(agg13/cnt @W1l + b1 + x@W1r); y2b = bf16(h1@W2l); z2 = h1@W2r
__global__ void fused1(const float* __restrict__ agg, const float* __restrict__ x,
                       const float* __restrict__ cntf,
                       const float* __restrict__ W1l, const float* __restrict__ b1,
                       const float* __restrict__ W1r, const float* __restrict__ W2l,
                       const float* __restrict__ W2r,
                       unsigned* __restrict__ y2b, float* __restrict__ z2) {
    __shared__ float sWl[208], sWr[208], sb[16], sA[128], sB[128];
    for (int i = threadIdx.x; i < 208; i += blockDim.x) { sWl[i] = W1l[i]; sWr[i] = W1r[i]; }
    for (int i = threadIdx.x; i < 128; i += blockDim.x) { sA[i] = W2l[i]; sB[i] = W2r[i]; }
    if (threadIdx.x < 16) sb[threadIdx.x] = b1[threadIdx.x];
    __syncthreads();
    int n = blockIdx.x * blockDim.x + threadIdx.x;
    if (n >= N_NODES) return;
    float inv = 1.0f / fmaxf(cntf[n], 1.0f);
    float a[13], xv[13];
#pragma unroll
    for (int i = 0; i < 13; i++) { a[i] = agg[n * 13 + i] * inv; xv[i] = x[n * 13 + i]; }
    float h[16];
#pragma unroll
    for (int o = 0; o < 16; o++) {
        float acc = sb[o];
#pragma unroll
        for (int i = 0; i < 13; i++) acc += a[i] * sWl[i * 16 + o] + xv[i] * sWr[i * 16 + o];
        h[o] = lrelu(acc);
    }
    float ya[8];
#pragma unroll
    for (int o2 = 0; o2 < 8; o2++) {
        float y = 0.0f, za = 0.0f;
#pragma unroll
        for (int o = 0; o < 16; o++) { y += h[o] * sA[o * 8 + o2]; za += h[o] * sB[o * 8 + o2]; }
        ya[o2] = y;
        z2[n * 8 + o2] = za;
    }
    uint4 out;
    out.x = pk(ya[0], ya[1]); out.y = pk(ya[2], ya[3]);
    out.z = pk(ya[4], ya[5]); out.w = pk(ya[6], ya[7]);
    *(uint4*)&y2b[(size_t)n * 4u] = out;
}

// h2 = lrelu(agg8/cnt + b2 + z2) (in place over z2); y3b = bf16(h2@W3l)
__global__ void fused2(const float* __restrict__ agg8, const float* __restrict__ cntf,
                       const float* __restrict__ b2, const float* __restrict__ W3l,
                       float* __restrict__ z2h2, unsigned* __restrict__ y3b) {
    __shared__ float sb[8], sW3[32];
    if (threadIdx.x < 8) sb[threadIdx.x] = b2[threadIdx.x];
    if (threadIdx.x < 32) sW3[threadIdx.x] = W3l[threadIdx.x];
    __syncthreads();
    int n = blockIdx.x * blockDim.x + threadIdx.x;
    if (n >= N_NODES) return;
    float inv = 1.0f / fmaxf(cntf[n], 1.0f);
    float h2v[8];
#pragma unroll
    for (int j = 0; j < 8; j++) {
        float v = agg8[n * 8 + j] * inv + sb[j] + z2h2[n * 8 + j];
        h2v[j] = lrelu(v);
        z2h2[n * 8 + j] = h2v[j];
    }
    float y[4];
#pragma unroll
    for (int k = 0; k < 4; k++) {
        float acc = 0.0f;
#pragma unroll
        for (int j = 0; j < 8; j++) acc += h2v[j] * sW3[j * 4 + k];
        y[k] = acc;
    }
    uint2 out;
    out.x = pk(y[0], y[1]); out.y = pk(y[2], y[3]);
    *(uint2*)&y3b[(size_t)n * 2u] = out;
}

// h3 = agg4/cnt + b3 + h2@W3r; pooled (sorted batch -> LDS window).
__global__ void pool_k(const float* __restrict__ agg4, const float* __restrict__ h2,
                       const float* __restrict__ cntf,
                       const float* __restrict__ W3r, const float* __restrict__ b3,
                       const int* __restrict__ batch,
                       float* __restrict__ pool, float* __restrict__ gcnt) {
    __shared__ float sW[32], sb[4];
    __shared__ float lp[16][4];
    __shared__ float lc[16];
    __shared__ int sbase;
    if (threadIdx.x < 32) sW[threadIdx.x] = W3r[threadIdx.x];
    if (threadIdx.x < 4) sb[threadIdx.x] = b3[threadIdx.x];
    if (threadIdx.x < 16) {
        lc[threadIdx.x] = 0.0f;
        for (int k = 0; k < 4; k++) lp[threadIdx.x][k] = 0.0f;
    }
    int n0 = blockIdx.x * blockDim.x;
    if (threadIdx.x == 0) sbase = batch[n0 < N_NODES ? n0 : N_NODES - 1];
    __syncthreads();
    int n = n0 + threadIdx.x;
    if (n < N_NODES) {
        int b = batch[n];
        float inv = 1.0f / fmaxf(cntf[n], 1.0f);
        float h2v[8];
#pragma unroll
        for (int j = 0; j < 8; j++) h2v[j] = h2[n * 8 + j];
        int off = b - sbase;
        bool local = (off >= 0 && off < 16);
#pragma unroll
        for (int k = 0; k < 4; k++) {
            float z = 0.0f;
#pragma unroll
            for (int j = 0; j < 8; j++) z += h2v[j] * sW[j * 4 + k];
            float v = agg4[n * 4 + k] * inv + sb[k] + z;
            if (local) atomicAdd(&lp[off][k], v);
            else atomicAdd(&pool[b * 4 + k], v);
        }
        if (local) atomicAdd(&lc[off], 1.0f);
        else atomicAdd(&gcnt[b], 1.0f);
    }
    __syncthreads();
    if (threadIdx.x < 16) {
        int b = sbase + threadIdx.x;
        float c = lc[threadIdx.x];
        if (c > 0.0f && b < N_GRAPHS) {
            atomicAdd(&gcnt[b], c);
            for (int k = 0; k < 4; k++) atomicAdd(&pool[b * 4 + k], lp[threadIdx.x][k]);
        }
    }
}

__global__ void final_k(const float* __restrict__ pool, const float* __restrict__ gcnt,
                        const float* __restrict__ Wc, const float* __restrict__ bc,
                        float* __restrict__ out) {
    int g = blockIdx.x * blockDim.x + threadIdx.x;
    if (g >= N_GRAPHS) return;
    float inv = 1.0f / fmaxf(gcnt[g], 1.0f);
    float acc = bc[0];
#pragma unroll
    for (int k = 0; k < 4; k++) {
        float ap = pool[g * 4 + k];
        acc += ap * inv * Wc[k] + ap * Wc[4 + k];
    }
    out[g] = acc;
}

extern "C" void kernel_launch(void* const* d_in, const int* in_sizes, int n_in,
                              void* d_out, int out_size, void* d_ws, size_t ws_size,
                              hipStream_t stream) {
    const float* x = (const float*)d_in[0];
    const int* ei = (const int*)d_in[1];
    const int* src = ei;
    const int* dst = ei + N_EDGES;
    const int* batch = (const int*)d_in[2];
    const float* W1l = (const float*)d_in[3];
    const float* b1 = (const float*)d_in[4];
    const float* W1r = (const float*)d_in[5];
    const float* W2l = (const float*)d_in[6];
    const float* b2 = (const float*)d_in[7];
    const float* W2r = (const float*)d_in[8];
    const float* W3l = (const float*)d_in[9];
    const float* b3 = (const float*)d_in[10];
    const float* W3r = (const float*)d_in[11];
    const float* Wc = (const float*)d_in[12];
    const float* bc = (const float*)d_in[13];
    float* out = (float*)d_out;

    const size_t N = N_NODES;
    unsigned* binned = (unsigned*)d_ws;             // NSUB*CAPQ u32 ~= 20 MB
    int* qcnt = (int*)(binned + (size_t)NSUB * CAPQ);  // 2048 ints
    float* fbase = (float*)(qcnt + 2048);
    float* agg = fbase;                         // 13N floats (reused 8N / 4N)
    float* cntf = fbase + 13 * N;               // N
    float* z2 = cntf + N;                       // 8N (becomes h2 in place)
    unsigned* x16b = (unsigned*)(z2 + 8 * N);   // 8N u32 (16 bf16/row)
    unsigned* y2b = x16b + 8 * N;               // 4N u32 (8 bf16/row)
    unsigned* y3b = y2b + 4 * N;                // 2N u32 (4 bf16/row)
    float* pool = (float*)(y3b + 2 * N);        // 2048
    float* gcnt = pool + N_GRAPHS * 4;          // 512

    const int TPB = 256;
    const int NB = (N_NODES + TPB - 1) / TPB;

    hipMemsetAsync(qcnt, 0, 2048 * sizeof(int), stream);
    hipMemsetAsync(pool, 0, N_GRAPHS * 5 * sizeof(float), stream);

    // Prep: bf16-pack x to 32-B rows; bin edges by (dst>>9, src>>16).
    pack_x<<<(N_NODES * 8 + TPB - 1) / TPB, TPB, 0, stream>>>(x, x16b);
    partition_k<<<PART_BLOCKS, TPB, 0, stream>>>(src, dst, qcnt, binned);

    // Layer 1: LDS-aggregate x16b (13 dims + degree), fused node linear.
    agg13_k<<<NBINS, 1024, 0, stream>>>(x16b, binned, qcnt, agg, cntf);
    fused1<<<NB, TPB, 0, stream>>>(agg, x, cntf, W1l, b1, W1r, W2l, W2r, y2b, z2);

    // Layer 2: LDS-aggregate y2b (8 dims), epilogue -> h2 (in z2), y3b.
    agg8_k<<<NBINS, 1024, 0, stream>>>(y2b, binned, qcnt, agg);
    fused2<<<NB, TPB, 0, stream>>>(agg, cntf, b2, W3l, z2, y3b);

    // Layer 3: LDS-aggregate y3b (4 dims), epilogue + pooling.
    agg4_k<<<NBINS, 1024, 0, stream>>>(y3b, binned, qcnt, agg);
    pool_k<<<NB, TPB, 0, stream>>>(agg, z2, cntf, W3r, b3, batch, pool, gcnt);

    final_k<<<2, TPB, 0, stream>>>(pool, gcnt, Wc, bc, out);
}

// Round 9
// 367.885 us; speedup vs baseline: 2.2724x; 2.2724x over previous
//
#include <hip/hip_runtime.h>

#define N_NODES 250000
#define N_EDGES 4000000
#define N_GRAPHS 512
#define NEG 0.01f
#define BINB 9
#define WIN 512
#define NBINS 489            // ceil(250000 / 512)
#define NSUB (NBINS * 4)     // dst-bin x src-quarter
#define CAPQ 2560            // per-sub-bin capacity: mean ~2045 + 9 sigma
#define PART_EPB 16384
#define PART_BLOCKS 245      // 245 * 16384 >= N_EDGES

__device__ __forceinline__ float lrelu(float v) { return v > 0.0f ? v : NEG * v; }
// bf16 pack (RNE) / unpack helpers, bit-level
__device__ __forceinline__ unsigned f2b(float f) {
    unsigned u = __float_as_uint(f);
    unsigned r = ((u >> 16) & 1u) + 0x7FFFu;
    return (u + r) >> 16;
}
__device__ __forceinline__ unsigned pk(float a, float b) { return f2b(a) | (f2b(b) << 16); }
__device__ __forceinline__ float blo(unsigned p) { return __uint_as_float(p << 16); }
__device__ __forceinline__ float bhi(unsigned p) { return __uint_as_float(p & 0xFFFF0000u); }

// ---- Pack x (13 f32) into x16b (16 bf16 = 32 B rows) -------------------
__global__ void pack_x(const float* __restrict__ x, unsigned* __restrict__ x16b) {
    int tid = blockIdx.x * blockDim.x + threadIdx.x;
    if (tid >= N_NODES * 8) return;
    int n = tid >> 3, d2 = tid & 7;
    int a = d2 * 2, b = a + 1;
    float va = (a < 13) ? x[n * 13 + a] : 0.0f;
    float vb = (b < 13) ? x[n * 13 + b] : 0.0f;
    x16b[tid] = pk(va, vb);
}

// ---- Edge binning into (dst-bin x src-quarter), 2-pass per block -------
__global__ void partition_k(const int* __restrict__ src, const int* __restrict__ dst,
                            int* __restrict__ qcnt, unsigned* __restrict__ binned) {
    __shared__ int hist[NSUB];   // pass1: counts; pass2: relative cursor
    __shared__ int base[NSUB];
    int t = threadIdx.x;
    for (int i = t; i < NSUB; i += 256) hist[i] = 0;
    __syncthreads();
    unsigned e0 = blockIdx.x * PART_EPB;
    for (int i = 0; i < PART_EPB / 256; i++) {
        unsigned e = e0 + (unsigned)i * 256u + t;
        if (e < N_EDGES) {
            int s = ((dst[e] >> BINB) << 2) | (src[e] >> 16);
            atomicAdd(&hist[s], 1);
        }
    }
    __syncthreads();
    for (int i = t; i < NSUB; i += 256) {
        int h = hist[i];
        base[i] = (h > 0) ? atomicAdd(&qcnt[i], h) : 0;
        hist[i] = 0;
    }
    __syncthreads();
    for (int i = 0; i < PART_EPB / 256; i++) {
        unsigned e = e0 + (unsigned)i * 256u + t;
        if (e < N_EDGES) {
            int d = dst[e], sv = src[e];
            int s = ((d >> BINB) << 2) | (sv >> 16);
            int pos = base[s] + atomicAdd(&hist[s], 1);
            binned[(size_t)s * CAPQ + pos] =
                ((unsigned)(d & (WIN - 1)) << 18) | (unsigned)sv;
        }
    }
}

// ---- Counting sort each sub-bin by dst; emit offsets + degrees ---------
__global__ __launch_bounds__(1024) void sort_bin_k(unsigned* __restrict__ binned,
                                                   const int* __restrict__ qcnt,
                                                   int* __restrict__ offs,
                                                   float* __restrict__ cntf) {
    __shared__ unsigned stg[CAPQ];
    __shared__ unsigned srt[CAPQ];
    __shared__ int hist[WIN];
    __shared__ int cur[WIN];
    __shared__ int scn[WIN];
    int t = threadIdx.x;
    int bin = blockIdx.x;
    int deg = 0;  // per-thread (t<WIN): degree of node bin*512+t
    for (int q = 0; q < 4; q++) {
        int sub = (bin << 2) | q;
        int cnt = qcnt[sub];
        unsigned* bp = binned + (size_t)sub * CAPQ;
        if (t < WIN) hist[t] = 0;
        __syncthreads();
        for (int i = t; i < cnt; i += 1024) {
            unsigned w = bp[i];
            stg[i] = w;
            atomicAdd(&hist[w >> 18], 1);
        }
        __syncthreads();
        // exclusive scan of hist into scn (Hillis-Steele, 512 lanes)
        if (t < WIN) scn[t] = hist[t];
        __syncthreads();
        for (int off = 1; off < WIN; off <<= 1) {
            int v = 0;
            if (t < WIN && t >= off) v = scn[t - off];
            __syncthreads();
            if (t < WIN) scn[t] += v;
            __syncthreads();
        }
        if (t < WIN) {
            int ex = scn[t] - hist[t];
            cur[t] = ex;
            offs[(size_t)sub * 513 + t] = ex;
            deg += hist[t];
        }
        if (t == 0) offs[(size_t)sub * 513 + WIN] = cnt;
        __syncthreads();
        for (int i = t; i < cnt; i += 1024) {
            unsigned w = stg[i];
            int pos = atomicAdd(&cur[w >> 18], 1);
            srt[pos] = w;
        }
        __syncthreads();
        for (int i = t; i < cnt; i += 1024) bp[i] = srt[i];
        __syncthreads();
    }
    if (t < WIN) {
        int n = (bin << BINB) + t;
        if (n < N_NODES) cntf[n] = (float)deg;
    }
}

// ---- Layer-1 aggregation: lane-pair owns a node, register acc ----------
__global__ __launch_bounds__(256) void agg13_k(const unsigned* __restrict__ x16b,
                                               const unsigned* __restrict__ binned,
                                               const int* __restrict__ offs,
                                               float* __restrict__ agg) {
    int t = threadIdx.x;
    int g = blockIdx.x * 128 + (t >> 1);   // node id
    int l = t & 1;                          // covers bf16 dims l*8 .. l*8+7
    if (g >= N_NODES) return;
    int bin = g >> BINB, f = g & (WIN - 1);
    float a0 = 0, a1 = 0, a2 = 0, a3 = 0, a4 = 0, a5 = 0, a6 = 0, a7 = 0;
#pragma unroll
    for (int q = 0; q < 4; q++) {
        int sub = (bin << 2) | q;
        const int* o = offs + (size_t)sub * 513;
        int s = o[f], e = o[f + 1];
        const unsigned* bp = binned + (size_t)sub * CAPQ;
        int k = s;
        for (; k + 4 <= e; k += 4) {
            unsigned w0 = bp[k], w1 = bp[k + 1], w2 = bp[k + 2], w3 = bp[k + 3];
            uint4 v0 = *(const uint4*)&x16b[(size_t)(w0 & 0x3FFFFu) * 8u + (unsigned)(l * 4)];
            uint4 v1 = *(const uint4*)&x16b[(size_t)(w1 & 0x3FFFFu) * 8u + (unsigned)(l * 4)];
            uint4 v2 = *(const uint4*)&x16b[(size_t)(w2 & 0x3FFFFu) * 8u + (unsigned)(l * 4)];
            uint4 v3 = *(const uint4*)&x16b[(size_t)(w3 & 0x3FFFFu) * 8u + (unsigned)(l * 4)];
            a0 += blo(v0.x) + blo(v1.x) + blo(v2.x) + blo(v3.x);
            a1 += bhi(v0.x) + bhi(v1.x) + bhi(v2.x) + bhi(v3.x);
            a2 += blo(v0.y) + blo(v1.y) + blo(v2.y) + blo(v3.y);
            a3 += bhi(v0.y) + bhi(v1.y) + bhi(v2.y) + bhi(v3.y);
            a4 += blo(v0.z) + blo(v1.z) + blo(v2.z) + blo(v3.z);
            a5 += bhi(v0.z) + bhi(v1.z) + bhi(v2.z) + bhi(v3.z);
            a6 += blo(v0.w) + blo(v1.w) + blo(v2.w) + blo(v3.w);
            a7 += bhi(v0.w) + bhi(v1.w) + bhi(v2.w) + bhi(v3.w);
        }
        for (; k < e; k++) {
            unsigned w = bp[k];
            uint4 v = *(const uint4*)&x16b[(size_t)(w & 0x3FFFFu) * 8u + (unsigned)(l * 4)];
            a0 += blo(v.x); a1 += bhi(v.x); a2 += blo(v.y); a3 += bhi(v.y);
            a4 += blo(v.z); a5 += bhi(v.z); a6 += blo(v.w); a7 += bhi(v.w);
        }
    }
    size_t base = (size_t)g * 13;
    if (l == 0) {
        agg[base + 0] = a0; agg[base + 1] = a1; agg[base + 2] = a2; agg[base + 3] = a3;
        agg[base + 4] = a4; agg[base + 5] = a5; agg[base + 6] = a6; agg[base + 7] = a7;
    } else {
        agg[base + 8] = a0; agg[base + 9] = a1; agg[base + 10] = a2;
        agg[base + 11] = a3; agg[base + 12] = a4;
    }
}

// ---- Layer-2 aggregation: lane owns a node (8 dims) --------------------
__global__ __launch_bounds__(256) void agg8_k(const unsigned* __restrict__ y2b,
                                              const unsigned* __restrict__ binned,
                                              const int* __restrict__ offs,
                                              float* __restrict__ agg) {
    int g = blockIdx.x * 256 + threadIdx.x;
    if (g >= N_NODES) return;
    int bin = g >> BINB, f = g & (WIN - 1);
    float a0 = 0, a1 = 0, a2 = 0, a3 = 0, a4 = 0, a5 = 0, a6 = 0, a7 = 0;
#pragma unroll
    for (int q = 0; q < 4; q++) {
        int sub = (bin << 2) | q;
        const int* o = offs + (size_t)sub * 513;
        int s = o[f], e = o[f + 1];
        const unsigned* bp = binned + (size_t)sub * CAPQ;
        int k = s;
        for (; k + 4 <= e; k += 4) {
            unsigned w0 = bp[k], w1 = bp[k + 1], w2 = bp[k + 2], w3 = bp[k + 3];
            uint4 v0 = *(const uint4*)&y2b[(size_t)(w0 & 0x3FFFFu) * 4u];
            uint4 v1 = *(const uint4*)&y2b[(size_t)(w1 & 0x3FFFFu) * 4u];
            uint4 v2 = *(const uint4*)&y2b[(size_t)(w2 & 0x3FFFFu) * 4u];
            uint4 v3 = *(const uint4*)&y2b[(size_t)(w3 & 0x3FFFFu) * 4u];
            a0 += blo(v0.x) + blo(v1.x) + blo(v2.x) + blo(v3.x);
            a1 += bhi(v0.x) + bhi(v1.x) + bhi(v2.x) + bhi(v3.x);
            a2 += blo(v0.y) + blo(v1.y) + blo(v2.y) + blo(v3.y);
            a3 += bhi(v0.y) + bhi(v1.y) + bhi(v2.y) + bhi(v3.y);
            a4 += blo(v0.z) + blo(v1.z) + blo(v2.z) + blo(v3.z);
            a5 += bhi(v0.z) + bhi(v1.z) + bhi(v2.z) + bhi(v3.z);
            a6 += blo(v0.w) + blo(v1.w) + blo(v2.w) + blo(v3.w);
            a7 += bhi(v0.w) + bhi(v1.w) + bhi(v2.w) + bhi(v3.w);
        }
        for (; k < e; k++) {
            uint4 v = *(const uint4*)&y2b[(size_t)(bp[k] & 0x3FFFFu) * 4u];
            a0 += blo(v.x); a1 += bhi(v.x); a2 += blo(v.y); a3 += bhi(v.y);
            a4 += blo(v.z); a5 += bhi(v.z); a6 += blo(v.w); a7 += bhi(v.w);
        }
    }
    float4 o1 = make_float4(a0, a1, a2, a3);
    float4 o2 = make_float4(a4, a5, a6, a7);
    *(float4*)&agg[(size_t)g * 8] = o1;
    *(float4*)&agg[(size_t)g * 8 + 4] = o2;
}

// ---- Layer-3 aggregation: lane owns a node (4 dims) --------------------
__global__ __launch_bounds__(256) void agg4_k(const unsigned* __restrict__ y3b,
                                              const unsigned* __restrict__ binned,
                                              const int* __restrict__ offs,
                                              float* __restrict__ agg) {
    int g = blockIdx.x * 256 + threadIdx.x;
    if (g >= N_NODES) return;
    int bin = g >> BINB, f = g & (WIN - 1);
    float a0 = 0, a1 = 0, a2 = 0, a3 = 0;
#pragma unroll
    for (int q = 0; q < 4; q++) {
        int sub = (bin << 2) | q;
        const int* o = offs + (size_t)sub * 513;
        int s = o[f], e = o[f + 1];
        const unsigned* bp = binned + (size_t)sub * CAPQ;
        int k = s;
        for (; k + 4 <= e; k += 4) {
            unsigned w0 = bp[k], w1 = bp[k + 1], w2 = bp[k + 2], w3 = bp[k + 3];
            uint2 v0 = *(const uint2*)&y3b[(size_t)(w0 & 0x3FFFFu) * 2u];
            uint2 v1 = *(const uint2*)&y3b[(size_t)(w1 & 0x3FFFFu) * 2u];
            uint2 v2 = *(const uint2*)&y3b[(size_t)(w2 & 0x3FFFFu) * 2u];
            uint2 v3 = *(const uint2*)&y3b[(size_t)(w3 & 0x3FFFFu) * 2u];
            a0 += blo(v0.x) + blo(v1.x) + blo(v2.x) + blo(v3.x);
            a1 += bhi(v0.x) + bhi(v1.x) + bhi(v2.x) + bhi(v3.x);
            a2 += blo(v0.y) + blo(v1.y) + blo(v2.y) + blo(v3.y);
            a3 += bhi(v0.y) + bhi(v1.y) + bhi(v2.y) + bhi(v3.y);
        }
        for (; k < e; k++) {
            uint2 v = *(const uint2*)&y3b[(size_t)(bp[k] & 0x3FFFFu) * 2u];
            a0 += blo(v.x); a1 += bhi(v.x); a2 += blo(v.y); a3 += bhi(v.y);
        }
    }
    *(float4*)&agg[(size_t)g * 4] = make_float4(a0, a1, a2, a3);
}

// ---- Node-side fused linears -------------------------------------------

// h1 = lrelu(agg13/cnt @W1l + b1 + x@W1r); y2b = bf16(h1@W2l); z2 = h1@W2r
__global__ void fused1(const float* __restrict__ agg, const float* __restrict__ x,
                       const float* __restrict__ cntf,
                       const float* __restrict__ W1l, const float* __restrict__ b1,
                       const float* __restrict__ W1r, const float* __restrict__ W2l,
                       const float* __restrict__ W2r,
                       unsigned* __restrict__ y2b, float* __restrict__ z2) {
    __shared__ float sWl[208], sWr[208], sb[16], sA[128], sB[128];
    for (int i = threadIdx.x; i < 208; i += blockDim.x) { sWl[i] = W1l[i]; sWr[i] = W1r[i]; }
    for (int i = threadIdx.x; i < 128; i += blockDim.x) { sA[i] = W2l[i]; sB[i] = W2r[i]; }
    if (threadIdx.x < 16) sb[threadIdx.x] = b1[threadIdx.x];
    __syncthreads();
    int n = blockIdx.x * blockDim.x + threadIdx.x;
    if (n >= N_NODES) return;
    float inv = 1.0f / fmaxf(cntf[n], 1.0f);
    float a[13], xv[13];
#pragma unroll
    for (int i = 0; i < 13; i++) { a[i] = agg[n * 13 + i] * inv; xv[i] = x[n * 13 + i]; }
    float h[16];
#pragma unroll
    for (int o = 0; o < 16; o++) {
        float acc = sb[o];
#pragma unroll
        for (int i = 0; i < 13; i++) acc += a[i] * sWl[i * 16 + o] + xv[i] * sWr[i * 16 + o];
        h[o] = lrelu(acc);
    }
    float ya[8];
#pragma unroll
    for (int o2 = 0; o2 < 8; o2++) {
        float y = 0.0f, za = 0.0f;
#pragma unroll
        for (int o = 0; o < 16; o++) { y += h[o] * sA[o * 8 + o2]; za += h[o] * sB[o * 8 + o2]; }
        ya[o2] = y;
        z2[n * 8 + o2] = za;
    }
    uint4 out;
    out.x = pk(ya[0], ya[1]); out.y = pk(ya[2], ya[3]);
    out.z = pk(ya[4], ya[5]); out.w = pk(ya[6], ya[7]);
    *(uint4*)&y2b[(size_t)n * 4u] = out;
}

// h2 = lrelu(agg8/cnt + b2 + z2) (in place over z2); y3b = bf16(h2@W3l)
__global__ void fused2(const float* __restrict__ agg8, const float* __restrict__ cntf,
                       const float* __restrict__ b2, const float* __restrict__ W3l,
                       float* __restrict__ z2h2, unsigned* __restrict__ y3b) {
    __shared__ float sb[8], sW3[32];
    if (threadIdx.x < 8) sb[threadIdx.x] = b2[threadIdx.x];
    if (threadIdx.x < 32) sW3[threadIdx.x] = W3l[threadIdx.x];
    __syncthreads();
    int n = blockIdx.x * blockDim.x + threadIdx.x;
    if (n >= N_NODES) return;
    float inv = 1.0f / fmaxf(cntf[n], 1.0f);
    float h2v[8];
#pragma unroll
    for (int j = 0; j < 8; j++) {
        float v = agg8[n * 8 + j] * inv + sb[j] + z2h2[n * 8 + j];
        h2v[j] = lrelu(v);
        z2h2[n * 8 + j] = h2v[j];
    }
    float y[4];
#pragma unroll
    for (int k = 0; k < 4; k++) {
        float acc = 0.0f;
#pragma unroll
        for (int j = 0; j < 8; j++) acc += h2v[j] * sW3[j * 4 + k];
        y[k] = acc;
    }
    uint2 out;
    out.x = pk(y[0], y[1]); out.y = pk(y[2], y[3]);
    *(uint2*)&y3b[(size_t)n * 2u] = out;
}

// h3 = agg4/cnt + b3 + h2@W3r; pooled (sorted batch -> LDS window).
__global__ void pool_k(const float* __restrict__ agg4, const float* __restrict__ h2,
                       const float* __restrict__ cntf,
                       const float* __restrict__ W3r, const float* __restrict__ b3,
                       const int* __restrict__ batch,
                       float* __restrict__ pool, float* __restrict__ gcnt) {
    __shared__ float sW[32], sb[4];
    __shared__ float lp[16][4];
    __shared__ float lc[16];
    __shared__ int sbase;
    if (threadIdx.x < 32) sW[threadIdx.x] = W3r[threadIdx.x];
    if (threadIdx.x < 4) sb[threadIdx.x] = b3[threadIdx.x];
    if (threadIdx.x < 16) {
        lc[threadIdx.x] = 0.0f;
        for (int k = 0; k < 4; k++) lp[threadIdx.x][k] = 0.0f;
    }
    int n0 = blockIdx.x * blockDim.x;
    if (threadIdx.x == 0) sbase = batch[n0 < N_NODES ? n0 : N_NODES - 1];
    __syncthreads();
    int n = n0 + threadIdx.x;
    if (n < N_NODES) {
        int b = batch[n];
        float inv = 1.0f / fmaxf(cntf[n], 1.0f);
        float h2v[8];
#pragma unroll
        for (int j = 0; j < 8; j++) h2v[j] = h2[n * 8 + j];
        int off = b - sbase;
        bool local = (off >= 0 && off < 16);
#pragma unroll
        for (int k = 0; k < 4; k++) {
            float z = 0.0f;
#pragma unroll
            for (int j = 0; j < 8; j++) z += h2v[j] * sW[j * 4 + k];
            float v = agg4[n * 4 + k] * inv + sb[k] + z;
            if (local) atomicAdd(&lp[off][k], v);
            else atomicAdd(&pool[b * 4 + k], v);
        }
        if (local) atomicAdd(&lc[off], 1.0f);
        else atomicAdd(&gcnt[b], 1.0f);
    }
    __syncthreads();
    if (threadIdx.x < 16) {
        int b = sbase + threadIdx.x;
        float c = lc[threadIdx.x];
        if (c > 0.0f && b < N_GRAPHS) {
            atomicAdd(&gcnt[b], c);
            for (int k = 0; k < 4; k++) atomicAdd(&pool[b * 4 + k], lp[threadIdx.x][k]);
        }
    }
}

__global__ void final_k(const float* __restrict__ pool, const float* __restrict__ gcnt,
                        const float* __restrict__ Wc, const float* __restrict__ bc,
                        float* __restrict__ out) {
    int g = blockIdx.x * blockDim.x + threadIdx.x;
    if (g >= N_GRAPHS) return;
    float inv = 1.0f / fmaxf(gcnt[g], 1.0f);
    float acc = bc[0];
#pragma unroll
    for (int k = 0; k < 4; k++) {
        float ap = pool[g * 4 + k];
        acc += ap * inv * Wc[k] + ap * Wc[4 + k];
    }
    out[g] = acc;
}

extern "C" void kernel_launch(void* const* d_in, const int* in_sizes, int n_in,
                              void* d_out, int out_size, void* d_ws, size_t ws_size,
                              hipStream_t stream) {
    const float* x = (const float*)d_in[0];
    const int* ei = (const int*)d_in[1];
    const int* src = ei;
    const int* dst = ei + N_EDGES;
    const int* batch = (const int*)d_in[2];
    const float* W1l = (const float*)d_in[3];
    const float* b1 = (const float*)d_in[4];
    const float* W1r = (const float*)d_in[5];
    const float* W2l = (const float*)d_in[6];
    const float* b2 = (const float*)d_in[7];
    const float* W2r = (const float*)d_in[8];
    const float* W3l = (const float*)d_in[9];
    const float* b3 = (const float*)d_in[10];
    const float* W3r = (const float*)d_in[11];
    const float* Wc = (const float*)d_in[12];
    const float* bc = (const float*)d_in[13];
    float* out = (float*)d_out;

    const size_t N = N_NODES;
    unsigned* binned = (unsigned*)d_ws;                 // NSUB*CAPQ u32 ~= 20 MB
    int* qcnt = (int*)(binned + (size_t)NSUB * CAPQ);   // 2048 ints
    int* offs = qcnt + 2048;                            // NSUB*513 ints ~= 4 MB
    float* fbase = (float*)(offs + (size_t)NSUB * 513);
    float* agg = fbase;                         // 13N floats (reused 8N / 4N)
    float* cntf = fbase + 13 * N;               // N
    float* z2 = cntf + N;                       // 8N (becomes h2 in place)
    unsigned* x16b = (unsigned*)(z2 + 8 * N);   // 8N u32 (16 bf16/row)
    unsigned* y2b = x16b + 8 * N;               // 4N u32 (8 bf16/row)
    unsigned* y3b = y2b + 4 * N;                // 2N u32 (4 bf16/row)
    float* pool = (float*)(y3b + 2 * N);        // 2048
    float* gcnt = pool + N_GRAPHS * 4;          // 512

    const int TPB = 256;
    const int NB = (N_NODES + TPB - 1) / TPB;

    hipMemsetAsync(qcnt, 0, 2048 * sizeof(int), stream);
    hipMemsetAsync(pool, 0, N_GRAPHS * 5 * sizeof(float), stream);

    // Prep: bf16-pack x; bin edges by (dst>>9, src-quarter); sort by dst.
    pack_x<<<(N_NODES * 8 + TPB - 1) / TPB, TPB, 0, stream>>>(x, x16b);
    partition_k<<<PART_BLOCKS, TPB, 0, stream>>>(src, dst, qcnt, binned);
    sort_bin_k<<<NBINS, 1024, 0, stream>>>(binned, qcnt, offs, cntf);

    // Layer 1: atomic-free per-node gather of x16b, fused node linear.
    agg13_k<<<(N_NODES + 127) / 128, TPB, 0, stream>>>(x16b, binned, offs, agg);
    fused1<<<NB, TPB, 0, stream>>>(agg, x, cntf, W1l, b1, W1r, W2l, W2r, y2b, z2);

    // Layer 2: per-node gather of y2b, epilogue -> h2 (in z2), y3b.
    agg8_k<<<NB, TPB, 0, stream>>>(y2b, binned, offs, agg);
    fused2<<<NB, TPB, 0, stream>>>(agg, cntf, b2, W3l, z2, y3b);

    // Layer 3: per-node gather of y3b, epilogue + pooling.
    agg4_k<<<NB, TPB, 0, stream>>>(y3b, binned, offs, agg);
    pool_k<<<NB, TPB, 0, stream>>>(agg, z2, cntf, W3r, b3, batch, pool, gcnt);

    final_k<<<2, TPB, 0, stream>>>(pool, gcnt, Wc, bc, out);
}

// Round 10
// 349.338 us; speedup vs baseline: 2.3931x; 1.0531x over previous
//
#include <hip/hip_runtime.h>

#define N_NODES 250000
#define N_EDGES 4000000
#define N_GRAPHS 512
#define NEG 0.01f
#define BINB 9
#define WIN 512
#define NBINS 489            // ceil(250000 / 512)
#define NSUB (NBINS * 4)     // dst-bin x src-quarter
#define CAPQ 2560            // per-sub-bin capacity: mean ~2045 + 11 sigma
#define PART_EPB 16384
#define PART_BLOCKS 245      // 245 * 16384 >= N_EDGES

__device__ __forceinline__ float lrelu(float v) { return v > 0.0f ? v : NEG * v; }
// bf16 pack (RNE) / unpack helpers, bit-level
__device__ __forceinline__ unsigned f2b(float f) {
    unsigned u = __float_as_uint(f);
    unsigned r = ((u >> 16) & 1u) + 0x7FFFu;
    return (u + r) >> 16;
}
__device__ __forceinline__ unsigned pk(float a, float b) { return f2b(a) | (f2b(b) << 16); }
__device__ __forceinline__ float blo(unsigned p) { return __uint_as_float(p << 16); }
__device__ __forceinline__ float bhi(unsigned p) { return __uint_as_float(p & 0xFFFF0000u); }

// ---- Pack x (13 f32) into x16b (16 bf16 = 32 B rows) -------------------
__global__ void pack_x(const float* __restrict__ x, unsigned* __restrict__ x16b) {
    int tid = blockIdx.x * blockDim.x + threadIdx.x;
    if (tid >= N_NODES * 8) return;
    int n = tid >> 3, d2 = tid & 7;
    int a = d2 * 2, b = a + 1;
    float va = (a < 13) ? x[n * 13 + a] : 0.0f;
    float vb = (b < 13) ? x[n * 13 + b] : 0.0f;
    x16b[tid] = pk(va, vb);
}

// ---- Edge binning into (dst-bin x src-quarter), 2-pass, 1024 thr -------
__global__ __launch_bounds__(1024) void partition_k(const int* __restrict__ src,
                                                    const int* __restrict__ dst,
                                                    int* __restrict__ qcnt,
                                                    unsigned* __restrict__ binned) {
    __shared__ int hist[NSUB];   // pass1: counts; pass2: relative cursor
    __shared__ int base[NSUB];
    int t = threadIdx.x;
    for (int i = t; i < NSUB; i += 1024) hist[i] = 0;
    __syncthreads();
    unsigned e0 = blockIdx.x * PART_EPB;
    for (int i = 0; i < PART_EPB / 1024; i++) {
        unsigned e = e0 + (unsigned)i * 1024u + t;
        if (e < N_EDGES) {
            int s = ((dst[e] >> BINB) << 2) | (src[e] >> 16);
            atomicAdd(&hist[s], 1);
        }
    }
    __syncthreads();
    for (int i = t; i < NSUB; i += 1024) {
        int h = hist[i];
        base[i] = (h > 0) ? atomicAdd(&qcnt[i], h) : 0;
        hist[i] = 0;
    }
    __syncthreads();
    for (int i = 0; i < PART_EPB / 1024; i++) {
        unsigned e = e0 + (unsigned)i * 1024u + t;
        if (e < N_EDGES) {
            int d = dst[e], sv = src[e];
            int s = ((d >> BINB) << 2) | (sv >> 16);
            int pos = base[s] + atomicAdd(&hist[s], 1);
            binned[(size_t)s * CAPQ + pos] =
                ((unsigned)(d & (WIN - 1)) << 18) | (unsigned)sv;
        }
    }
}

// ---- Counting sort each sub-bin by dst + fused layer-1 aggregation -----
// Thread pair (f = t&511, l = t>>9) owns node bin*512+f, bf16 dims l*8..l*8+7.
__global__ __launch_bounds__(1024) void sortagg_k(const unsigned* __restrict__ x16b,
                                                  unsigned* __restrict__ binned,
                                                  const int* __restrict__ qcnt,
                                                  int* __restrict__ offs,
                                                  float* __restrict__ cntf,
                                                  float* __restrict__ agg) {
    __shared__ unsigned stg[CAPQ];
    __shared__ unsigned srt[CAPQ];
    __shared__ int hist[WIN];
    __shared__ int cur[WIN];
    __shared__ int scn[WIN];
    int t = threadIdx.x;
    int bin = blockIdx.x;
    int f = t & (WIN - 1), l = t >> 9;
    float a0 = 0, a1 = 0, a2 = 0, a3 = 0, a4 = 0, a5 = 0, a6 = 0, a7 = 0;
    int deg = 0;  // maintained by l==0 thread of each node
    for (int q = 0; q < 4; q++) {
        int sub = (bin << 2) | q;
        int cnt = qcnt[sub];
        unsigned* bp = binned + (size_t)sub * CAPQ;
        if (t < WIN) hist[t] = 0;
        __syncthreads();
        for (int i = t; i < cnt; i += 1024) {
            unsigned w = bp[i];
            stg[i] = w;
            atomicAdd(&hist[w >> 18], 1);
        }
        __syncthreads();
        if (t < WIN) scn[t] = hist[t];
        __syncthreads();
        for (int off = 1; off < WIN; off <<= 1) {
            int v = 0;
            if (t < WIN && t >= off) v = scn[t - off];
            __syncthreads();
            if (t < WIN) scn[t] += v;
            __syncthreads();
        }
        if (t < WIN) {
            int ex = scn[t] - hist[t];
            cur[t] = ex;
            offs[(size_t)sub * 513 + t] = ex;
            deg += hist[t];
        }
        if (t == 0) offs[(size_t)sub * 513 + WIN] = cnt;
        __syncthreads();
        for (int i = t; i < cnt; i += 1024) {
            unsigned w = stg[i];
            int pos = atomicAdd(&cur[w >> 18], 1);
            srt[pos] = w;
        }
        __syncthreads();
        // write sorted list back (for layers 2/3)
        for (int i = t; i < cnt; i += 1024) bp[i] = srt[i];
        // fused layer-1 gather-accumulate from LDS-resident sorted run
        int e_ = cur[f];           // cursor advanced to run end
        int s_ = e_ - hist[f];
        int k = s_;
        for (; k + 4 <= e_; k += 4) {
            unsigned w0 = srt[k], w1 = srt[k + 1], w2 = srt[k + 2], w3 = srt[k + 3];
            uint4 v0 = *(const uint4*)&x16b[(size_t)(w0 & 0x3FFFFu) * 8u + (unsigned)(l * 4)];
            uint4 v1 = *(const uint4*)&x16b[(size_t)(w1 & 0x3FFFFu) * 8u + (unsigned)(l * 4)];
            uint4 v2 = *(const uint4*)&x16b[(size_t)(w2 & 0x3FFFFu) * 8u + (unsigned)(l * 4)];
            uint4 v3 = *(const uint4*)&x16b[(size_t)(w3 & 0x3FFFFu) * 8u + (unsigned)(l * 4)];
            a0 += blo(v0.x) + blo(v1.x) + blo(v2.x) + blo(v3.x);
            a1 += bhi(v0.x) + bhi(v1.x) + bhi(v2.x) + bhi(v3.x);
            a2 += blo(v0.y) + blo(v1.y) + blo(v2.y) + blo(v3.y);
            a3 += bhi(v0.y) + bhi(v1.y) + bhi(v2.y) + bhi(v3.y);
            a4 += blo(v0.z) + blo(v1.z) + blo(v2.z) + blo(v3.z);
            a5 += bhi(v0.z) + bhi(v1.z) + bhi(v2.z) + bhi(v3.z);
            a6 += blo(v0.w) + blo(v1.w) + blo(v2.w) + blo(v3.w);
            a7 += bhi(v0.w) + bhi(v1.w) + bhi(v2.w) + bhi(v3.w);
        }
        for (; k < e_; k++) {
            unsigned w = srt[k];
            uint4 v = *(const uint4*)&x16b[(size_t)(w & 0x3FFFFu) * 8u + (unsigned)(l * 4)];
            a0 += blo(v.x); a1 += bhi(v.x); a2 += blo(v.y); a3 += bhi(v.y);
            a4 += blo(v.z); a5 += bhi(v.z); a6 += blo(v.w); a7 += bhi(v.w);
        }
        __syncthreads();  // before stg/srt/hist reuse in next quarter
    }
    int g = (bin << BINB) + f;
    if (g < N_NODES) {
        size_t b = (size_t)g * 13;
        if (l == 0) {
            agg[b + 0] = a0; agg[b + 1] = a1; agg[b + 2] = a2; agg[b + 3] = a3;
            agg[b + 4] = a4; agg[b + 5] = a5; agg[b + 6] = a6; agg[b + 7] = a7;
            cntf[g] = (float)deg;
        } else {
            // dims 8..12 (13..15 are zero pad)
            agg[b + 8] = a0; agg[b + 9] = a1; agg[b + 10] = a2;
            agg[b + 11] = a3; agg[b + 12] = a4;
        }
    }
}

// ---- Layer-2 aggregation: lane owns a node (8 dims) --------------------
__global__ __launch_bounds__(256) void agg8_k(const unsigned* __restrict__ y2b,
                                              const unsigned* __restrict__ binned,
                                              const int* __restrict__ offs,
                                              float* __restrict__ agg) {
    int g = blockIdx.x * 256 + threadIdx.x;
    if (g >= N_NODES) return;
    int bin = g >> BINB, f = g & (WIN - 1);
    float a0 = 0, a1 = 0, a2 = 0, a3 = 0, a4 = 0, a5 = 0, a6 = 0, a7 = 0;
#pragma unroll
    for (int q = 0; q < 4; q++) {
        int sub = (bin << 2) | q;
        const int* o = offs + (size_t)sub * 513;
        int s = o[f], e = o[f + 1];
        const unsigned* bp = binned + (size_t)sub * CAPQ;
        int k = s;
        for (; k + 4 <= e; k += 4) {
            unsigned w0 = bp[k], w1 = bp[k + 1], w2 = bp[k + 2], w3 = bp[k + 3];
            uint4 v0 = *(const uint4*)&y2b[(size_t)(w0 & 0x3FFFFu) * 4u];
            uint4 v1 = *(const uint4*)&y2b[(size_t)(w1 & 0x3FFFFu) * 4u];
            uint4 v2 = *(const uint4*)&y2b[(size_t)(w2 & 0x3FFFFu) * 4u];
            uint4 v3 = *(const uint4*)&y2b[(size_t)(w3 & 0x3FFFFu) * 4u];
            a0 += blo(v0.x) + blo(v1.x) + blo(v2.x) + blo(v3.x);
            a1 += bhi(v0.x) + bhi(v1.x) + bhi(v2.x) + bhi(v3.x);
            a2 += blo(v0.y) + blo(v1.y) + blo(v2.y) + blo(v3.y);
            a3 += bhi(v0.y) + bhi(v1.y) + bhi(v2.y) + bhi(v3.y);
            a4 += blo(v0.z) + blo(v1.z) + blo(v2.z) + blo(v3.z);
            a5 += bhi(v0.z) + bhi(v1.z) + bhi(v2.z) + bhi(v3.z);
            a6 += blo(v0.w) + blo(v1.w) + blo(v2.w) + blo(v3.w);
            a7 += bhi(v0.w) + bhi(v1.w) + bhi(v2.w) + bhi(v3.w);
        }
        for (; k < e; k++) {
            uint4 v = *(const uint4*)&y2b[(size_t)(bp[k] & 0x3FFFFu) * 4u];
            a0 += blo(v.x); a1 += bhi(v.x); a2 += blo(v.y); a3 += bhi(v.y);
            a4 += blo(v.z); a5 += bhi(v.z); a6 += blo(v.w); a7 += bhi(v.w);
        }
    }
    *(float4*)&agg[(size_t)g * 8] = make_float4(a0, a1, a2, a3);
    *(float4*)&agg[(size_t)g * 8 + 4] = make_float4(a4, a5, a6, a7);
}

// ---- Layer-3 aggregation: lane owns a node (4 dims) --------------------
__global__ __launch_bounds__(256) void agg4_k(const unsigned* __restrict__ y3b,
                                              const unsigned* __restrict__ binned,
                                              const int* __restrict__ offs,
                                              float* __restrict__ agg) {
    int g = blockIdx.x * 256 + threadIdx.x;
    if (g >= N_NODES) return;
    int bin = g >> BINB, f = g & (WIN - 1);
    float a0 = 0, a1 = 0, a2 = 0, a3 = 0;
#pragma unroll
    for (int q = 0; q < 4; q++) {
        int sub = (bin << 2) | q;
        const int* o = offs + (size_t)sub * 513;
        int s = o[f], e = o[f + 1];
        const unsigned* bp = binned + (size_t)sub * CAPQ;
        int k = s;
        for (; k + 4 <= e; k += 4) {
            unsigned w0 = bp[k], w1 = bp[k + 1], w2 = bp[k + 2], w3 = bp[k + 3];
            uint2 v0 = *(const uint2*)&y3b[(size_t)(w0 & 0x3FFFFu) * 2u];
            uint2 v1 = *(const uint2*)&y3b[(size_t)(w1 & 0x3FFFFu) * 2u];
            uint2 v2 = *(const uint2*)&y3b[(size_t)(w2 & 0x3FFFFu) * 2u];
            uint2 v3 = *(const uint2*)&y3b[(size_t)(w3 & 0x3FFFFu) * 2u];
            a0 += blo(v0.x) + blo(v1.x) + blo(v2.x) + blo(v3.x);
            a1 += bhi(v0.x) + bhi(v1.x) + bhi(v2.x) + bhi(v3.x);
            a2 += blo(v0.y) + blo(v1.y) + blo(v2.y) + blo(v3.y);
            a3 += bhi(v0.y) + bhi(v1.y) + bhi(v2.y) + bhi(v3.y);
        }
        for (; k < e; k++) {
            uint2 v = *(const uint2*)&y3b[(size_t)(bp[k] & 0x3FFFFu) * 2u];
            a0 += blo(v.x); a1 += bhi(v.x); a2 += blo(v.y); a3 += bhi(v.y);
        }
    }
    *(float4*)&agg[(size_t)g * 4] = make_float4(a0, a1, a2, a3);
}

// ---- Node-side fused linears -------------------------------------------

// h1 = lrelu(agg13/cnt @W1l + b1 + x@W1r); y2b = bf16(h1@W2l); z2 = h1@W2r
__global__ void fused1(const float* __restrict__ agg, const float* __restrict__ x,
                       const float* __restrict__ cntf,
                       const float* __restrict__ W1l, const float* __restrict__ b1,
                       const float* __restrict__ W1r, const float* __restrict__ W2l,
                       const float* __restrict__ W2r,
                       unsigned* __restrict__ y2b, float* __restrict__ z2) {
    __shared__ float sWl[208], sWr[208], sb[16], sA[128], sB[128];
    for (int i = threadIdx.x; i < 208; i += blockDim.x) { sWl[i] = W1l[i]; sWr[i] = W1r[i]; }
    for (int i = threadIdx.x; i < 128; i += blockDim.x) { sA[i] = W2l[i]; sB[i] = W2r[i]; }
    if (threadIdx.x < 16) sb[threadIdx.x] = b1[threadIdx.x];
    __syncthreads();
    int n = blockIdx.x * blockDim.x + threadIdx.x;
    if (n >= N_NODES) return;
    float inv = 1.0f / fmaxf(cntf[n], 1.0f);
    float a[13], xv[13];
#pragma unroll
    for (int i = 0; i < 13; i++) { a[i] = agg[n * 13 + i] * inv; xv[i] = x[n * 13 + i]; }
    float h[16];
#pragma unroll
    for (int o = 0; o < 16; o++) {
        float acc = sb[o];
#pragma unroll
        for (int i = 0; i < 13; i++) acc += a[i] * sWl[i * 16 + o] + xv[i] * sWr[i * 16 + o];
        h[o] = lrelu(acc);
    }
    float ya[8];
#pragma unroll
    for (int o2 = 0; o2 < 8; o2++) {
        float y = 0.0f, za = 0.0f;
#pragma unroll
        for (int o = 0; o < 16; o++) { y += h[o] * sA[o * 8 + o2]; za += h[o] * sB[o * 8 + o2]; }
        ya[o2] = y;
        z2[n * 8 + o2] = za;
    }
    uint4 out;
    out.x = pk(ya[0], ya[1]); out.y = pk(ya[2], ya[3]);
    out.z = pk(ya[4], ya[5]); out.w = pk(ya[6], ya[7]);
    *(uint4*)&y2b[(size_t)n * 4u] = out;
}

// h2 = lrelu(agg8/cnt + b2 + z2) (in place over z2); y3b = bf16(h2@W3l)
__global__ void fused2(const float* __restrict__ agg8, const float* __restrict__ cntf,
                       const float* __restrict__ b2, const float* __restrict__ W3l,
                       float* __restrict__ z2h2, unsigned* __restrict__ y3b) {
    __shared__ float sb[8], sW3[32];
    if (threadIdx.x < 8) sb[threadIdx.x] = b2[threadIdx.x];
    if (threadIdx.x < 32) sW3[threadIdx.x] = W3l[threadIdx.x];
    __syncthreads();
    int n = blockIdx.x * blockDim.x + threadIdx.x;
    if (n >= N_NODES) return;
    float inv = 1.0f / fmaxf(cntf[n], 1.0f);
    float h2v[8];
#pragma unroll
    for (int j = 0; j < 8; j++) {
        float v = agg8[n * 8 + j] * inv + sb[j] + z2h2[n * 8 + j];
        h2v[j] = lrelu(v);
        z2h2[n * 8 + j] = h2v[j];
    }
    float y[4];
#pragma unroll
    for (int k = 0; k < 4; k++) {
        float acc = 0.0f;
#pragma unroll
        for (int j = 0; j < 8; j++) acc += h2v[j] * sW3[j * 4 + k];
        y[k] = acc;
    }
    uint2 out;
    out.x = pk(y[0], y[1]); out.y = pk(y[2], y[3]);
    *(uint2*)&y3b[(size_t)n * 2u] = out;
}

// h3 = agg4/cnt + b3 + h2@W3r; pooled (sorted batch -> LDS window).
__global__ void pool_k(const float* __restrict__ agg4, const float* __restrict__ h2,
                       const float* __restrict__ cntf,
                       const float* __restrict__ W3r, const float* __restrict__ b3,
                       const int* __restrict__ batch,
                       float* __restrict__ pool, float* __restrict__ gcnt) {
    __shared__ float sW[32], sb[4];
    __shared__ float lp[16][4];
    __shared__ float lc[16];
    __shared__ int sbase;
    if (threadIdx.x < 32) sW[threadIdx.x] = W3r[threadIdx.x];
    if (threadIdx.x < 4) sb[threadIdx.x] = b3[threadIdx.x];
    if (threadIdx.x < 16) {
        lc[threadIdx.x] = 0.0f;
        for (int k = 0; k < 4; k++) lp[threadIdx.x][k] = 0.0f;
    }
    int n0 = blockIdx.x * blockDim.x;
    if (threadIdx.x == 0) sbase = batch[n0 < N_NODES ? n0 : N_NODES - 1];
    __syncthreads();
    int n = n0 + threadIdx.x;
    if (n < N_NODES) {
        int b = batch[n];
        float inv = 1.0f / fmaxf(cntf[n], 1.0f);
        float h2v[8];
#pragma unroll
        for (int j = 0; j < 8; j++) h2v[j] = h2[n * 8 + j];
        int off = b - sbase;
        bool local = (off >= 0 && off < 16);
#pragma unroll
        for (int k = 0; k < 4; k++) {
            float z = 0.0f;
#pragma unroll
            for (int j = 0; j < 8; j++) z += h2v[j] * sW[j * 4 + k];
            float v = agg4[n * 4 + k] * inv + sb[k] + z;
            if (local) atomicAdd(&lp[off][k], v);
            else atomicAdd(&pool[b * 4 + k], v);
        }
        if (local) atomicAdd(&lc[off], 1.0f);
        else atomicAdd(&gcnt[b], 1.0f);
    }
    __syncthreads();
    if (threadIdx.x < 16) {
        int b = sbase + threadIdx.x;
        float c = lc[threadIdx.x];
        if (c > 0.0f && b < N_GRAPHS) {
            atomicAdd(&gcnt[b], c);
            for (int k = 0; k < 4; k++) atomicAdd(&pool[b * 4 + k], lp[threadIdx.x][k]);
        }
    }
}

__global__ void final_k(const float* __restrict__ pool, const float* __restrict__ gcnt,
                        const float* __restrict__ Wc, const float* __restrict__ bc,
                        float* __restrict__ out) {
    int g = blockIdx.x * blockDim.x + threadIdx.x;
    if (g >= N_GRAPHS) return;
    float inv = 1.0f / fmaxf(gcnt[g], 1.0f);
    float acc = bc[0];
#pragma unroll
    for (int k = 0; k < 4; k++) {
        float ap = pool[g * 4 + k];
        acc += ap * inv * Wc[k] + ap * Wc[4 + k];
    }
    out[g] = acc;
}

extern "C" void kernel_launch(void* const* d_in, const int* in_sizes, int n_in,
                              void* d_out, int out_size, void* d_ws, size_t ws_size,
                              hipStream_t stream) {
    const float* x = (const float*)d_in[0];
    const int* ei = (const int*)d_in[1];
    const int* src = ei;
    const int* dst = ei + N_EDGES;
    const int* batch = (const int*)d_in[2];
    const float* W1l = (const float*)d_in[3];
    const float* b1 = (const float*)d_in[4];
    const float* W1r = (const float*)d_in[5];
    const float* W2l = (const float*)d_in[6];
    const float* b2 = (const float*)d_in[7];
    const float* W2r = (const float*)d_in[8];
    const float* W3l = (const float*)d_in[9];
    const float* b3 = (const float*)d_in[10];
    const float* W3r = (const float*)d_in[11];
    const float* Wc = (const float*)d_in[12];
    const float* bc = (const float*)d_in[13];
    float* out = (float*)d_out;

    const size_t N = N_NODES;
    unsigned* binned = (unsigned*)d_ws;                 // NSUB*CAPQ u32 ~= 20 MB
    int* qcnt = (int*)(binned + (size_t)NSUB * CAPQ);   // 2048 ints
    int* offs = qcnt + 2048;                            // NSUB*513 ints ~= 4 MB
    float* fbase = (float*)(offs + (size_t)NSUB * 513);
    float* agg = fbase;                         // 13N floats (reused 8N / 4N)
    float* cntf = fbase + 13 * N;               // N
    float* z2 = cntf + N;                       // 8N (becomes h2 in place)
    unsigned* x16b = (unsigned*)(z2 + 8 * N);   // 8N u32 (16 bf16/row)
    unsigned* y2b = x16b + 8 * N;               // 4N u32 (8 bf16/row)
    unsigned* y3b = y2b + 4 * N;                // 2N u32 (4 bf16/row)
    float* pool = (float*)(y3b + 2 * N);        // 2048
    float* gcnt = pool + N_GRAPHS * 4;          // 512

    const int TPB = 256;
    const int NB = (N_NODES + TPB - 1) / TPB;

    hipMemsetAsync(qcnt, 0, 2048 * sizeof(int), stream);
    hipMemsetAsync(pool, 0, N_GRAPHS * 5 * sizeof(float), stream);

    // Prep: bf16-pack x; bin edges by (dst>>9, src-quarter).
    pack_x<<<(N_NODES * 8 + TPB - 1) / TPB, TPB, 0, stream>>>(x, x16b);
    partition_k<<<PART_BLOCKS, 1024, 0, stream>>>(src, dst, qcnt, binned);

    // Sort each sub-bin by dst + fused layer-1 aggregation; then node linear.
    sortagg_k<<<NBINS, 1024, 0, stream>>>(x16b, binned, qcnt, offs, cntf, agg);
    fused1<<<NB, TPB, 0, stream>>>(agg, x, cntf, W1l, b1, W1r, W2l, W2r, y2b, z2);

    // Layer 2: per-node gather of y2b, epilogue -> h2 (in z2), y3b.
    agg8_k<<<NB, TPB, 0, stream>>>(y2b, binned, offs, agg);
    fused2<<<NB, TPB, 0, stream>>>(agg, cntf, b2, W3l, z2, y3b);

    // Layer 3: per-node gather of y3b, epilogue + pooling.
    agg4_k<<<NB, TPB, 0, stream>>>(y3b, binned, offs, agg);
    pool_k<<<NB, TPB, 0, stream>>>(agg, z2, cntf, W3r, b3, batch, pool, gcnt);

    final_k<<<2, TPB, 0, stream>>>(pool, gcnt, Wc, bc, out);
}

// Round 11
// 318.366 us; speedup vs baseline: 2.6259x; 1.0973x over previous
//
#include <hip/hip_runtime.h>

#define N_NODES 250000
#define N_EDGES 4000000
#define N_GRAPHS 512
#define NEG 0.01f
#define BINB 9
#define WIN 512
#define NBINS 489            // ceil(250000 / 512)
#define NSUB (NBINS * 4)     // dst-bin x src-quarter
#define CAPQ 2560            // per-sub-bin capacity: mean ~2045 + 11 sigma
#define PART_EPB 8192
#define PART_BLOCKS 489      // 489 * 8192 >= N_EDGES

__device__ __forceinline__ float lrelu(float v) { return v > 0.0f ? v : NEG * v; }
__device__ __forceinline__ unsigned f2b(float f) {
    unsigned u = __float_as_uint(f);
    unsigned r = ((u >> 16) & 1u) + 0x7FFFu;
    return (u + r) >> 16;
}
__device__ __forceinline__ unsigned pk(float a, float b) { return f2b(a) | (f2b(b) << 16); }
__device__ __forceinline__ float blo(unsigned p) { return __uint_as_float(p << 16); }
__device__ __forceinline__ float bhi(unsigned p) { return __uint_as_float(p & 0xFFFF0000u); }

// ---- Pack x into x16b (16 bf16 = 32 B rows); block 0 zeroes qcnt -------
__global__ void pack_x(const float* __restrict__ x, unsigned* __restrict__ x16b,
                       int* __restrict__ qcnt) {
    if (blockIdx.x == 0) {
        for (int i = threadIdx.x; i < NSUB; i += 256) qcnt[i] = 0;
    }
    int tid = blockIdx.x * blockDim.x + threadIdx.x;
    if (tid >= N_NODES * 8) return;
    int n = tid >> 3, d2 = tid & 7;
    int a = d2 * 2, b = a + 1;
    float va = (a < 13) ? x[n * 13 + a] : 0.0f;
    float vb = (b < 13) ? x[n * 13 + b] : 0.0f;
    x16b[tid] = pk(va, vb);
}

// ---- Edge binning into (dst-bin x src-quarter), 2-pass, 1024 thr -------
__global__ __launch_bounds__(1024) void partition_k(const int* __restrict__ src,
                                                    const int* __restrict__ dst,
                                                    int* __restrict__ qcnt,
                                                    unsigned* __restrict__ binned) {
    __shared__ int hist[NSUB];
    __shared__ int base[NSUB];
    int t = threadIdx.x;
    for (int i = t; i < NSUB; i += 1024) hist[i] = 0;
    __syncthreads();
    unsigned e0 = blockIdx.x * PART_EPB;
    for (int i = 0; i < PART_EPB / 1024; i++) {
        unsigned e = e0 + (unsigned)i * 1024u + t;
        if (e < N_EDGES) {
            int s = ((dst[e] >> BINB) << 2) | (src[e] >> 16);
            atomicAdd(&hist[s], 1);
        }
    }
    __syncthreads();
    for (int i = t; i < NSUB; i += 1024) {
        int h = hist[i];
        base[i] = (h > 0) ? atomicAdd(&qcnt[i], h) : 0;
        hist[i] = 0;
    }
    __syncthreads();
    for (int i = 0; i < PART_EPB / 1024; i++) {
        unsigned e = e0 + (unsigned)i * 1024u + t;
        if (e < N_EDGES) {
            int d = dst[e], sv = src[e];
            int s = ((d >> BINB) << 2) | (sv >> 16);
            int pos = base[s] + atomicAdd(&hist[s], 1);
            binned[(size_t)s * CAPQ + pos] =
                ((unsigned)(d & (WIN - 1)) << 18) | (unsigned)sv;
        }
    }
}

// ---- Counting sort each sub-bin by dst + fused layer-1 aggregation -----
__global__ __launch_bounds__(1024) void sortagg_k(const unsigned* __restrict__ x16b,
                                                  unsigned* __restrict__ binned,
                                                  const int* __restrict__ qcnt,
                                                  int* __restrict__ offs,
                                                  float* __restrict__ cntf,
                                                  float* __restrict__ agg) {
    __shared__ unsigned stg[CAPQ];
    __shared__ unsigned srt[CAPQ];
    __shared__ int hist[WIN];
    __shared__ int cur[WIN];
    __shared__ int wsum[8];
    int t = threadIdx.x;
    int bin = blockIdx.x;
    int f = t & (WIN - 1), l = t >> 9;
    int lane = t & 63, wv = t >> 6;   // wave id 0..15; scan uses waves 0..7
    float a0 = 0, a1 = 0, a2 = 0, a3 = 0, a4 = 0, a5 = 0, a6 = 0, a7 = 0;
    int deg = 0;
    for (int q = 0; q < 4; q++) {
        int sub = (bin << 2) | q;
        int cnt = qcnt[sub];
        unsigned* bp = binned + (size_t)sub * CAPQ;
        if (t < WIN) hist[t] = 0;
        __syncthreads();
        for (int i = t; i < cnt; i += 1024) {
            unsigned w = bp[i];
            stg[i] = w;
            atomicAdd(&hist[w >> 18], 1);
        }
        __syncthreads();
        // wave-shuffle inclusive scan over 512 counters (waves 0..7)
        int v = (t < WIN) ? hist[t] : 0;
#pragma unroll
        for (int d = 1; d < 64; d <<= 1) {
            int u = __shfl_up(v, d, 64);
            if (lane >= d) v += u;
        }
        if (t < WIN && lane == 63) wsum[wv] = v;
        __syncthreads();
        if (t == 0) {
            int r = 0;
#pragma unroll
            for (int i = 0; i < 8; i++) { int s = wsum[i]; wsum[i] = r; r += s; }
        }
        __syncthreads();
        if (t < WIN) {
            int incl = v + wsum[wv];
            int ex = incl - hist[t];
            cur[t] = ex;
            offs[(size_t)sub * 513 + t] = ex;
            deg += hist[t];
        }
        if (t == 0) offs[(size_t)sub * 513 + WIN] = cnt;
        __syncthreads();
        for (int i = t; i < cnt; i += 1024) {
            unsigned w = stg[i];
            int pos = atomicAdd(&cur[w >> 18], 1);
            srt[pos] = w;
        }
        __syncthreads();
        for (int i = t; i < cnt; i += 1024) bp[i] = srt[i];
        // fused layer-1 gather from LDS-resident sorted run
        int e_ = cur[f];
        int s_ = e_ - hist[f];
        int k = s_;
        for (; k + 4 <= e_; k += 4) {
            unsigned w0 = srt[k], w1 = srt[k + 1], w2 = srt[k + 2], w3 = srt[k + 3];
            uint4 v0 = *(const uint4*)&x16b[(size_t)(w0 & 0x3FFFFu) * 8u + (unsigned)(l * 4)];
            uint4 v1 = *(const uint4*)&x16b[(size_t)(w1 & 0x3FFFFu) * 8u + (unsigned)(l * 4)];
            uint4 v2 = *(const uint4*)&x16b[(size_t)(w2 & 0x3FFFFu) * 8u + (unsigned)(l * 4)];
            uint4 v3 = *(const uint4*)&x16b[(size_t)(w3 & 0x3FFFFu) * 8u + (unsigned)(l * 4)];
            a0 += blo(v0.x) + blo(v1.x) + blo(v2.x) + blo(v3.x);
            a1 += bhi(v0.x) + bhi(v1.x) + bhi(v2.x) + bhi(v3.x);
            a2 += blo(v0.y) + blo(v1.y) + blo(v2.y) + blo(v3.y);
            a3 += bhi(v0.y) + bhi(v1.y) + bhi(v2.y) + bhi(v3.y);
            a4 += blo(v0.z) + blo(v1.z) + blo(v2.z) + blo(v3.z);
            a5 += bhi(v0.z) + bhi(v1.z) + bhi(v2.z) + bhi(v3.z);
            a6 += blo(v0.w) + blo(v1.w) + blo(v2.w) + blo(v3.w);
            a7 += bhi(v0.w) + bhi(v1.w) + bhi(v2.w) + bhi(v3.w);
        }
        for (; k < e_; k++) {
            unsigned w = srt[k];
            uint4 v4 = *(const uint4*)&x16b[(size_t)(w & 0x3FFFFu) * 8u + (unsigned)(l * 4)];
            a0 += blo(v4.x); a1 += bhi(v4.x); a2 += blo(v4.y); a3 += bhi(v4.y);
            a4 += blo(v4.z); a5 += bhi(v4.z); a6 += blo(v4.w); a7 += bhi(v4.w);
        }
        __syncthreads();
    }
    int g = (bin << BINB) + f;
    if (g < N_NODES) {
        size_t b = (size_t)g * 13;
        if (l == 0) {
            agg[b + 0] = a0; agg[b + 1] = a1; agg[b + 2] = a2; agg[b + 3] = a3;
            agg[b + 4] = a4; agg[b + 5] = a5; agg[b + 6] = a6; agg[b + 7] = a7;
            cntf[g] = (float)deg;
        } else {
            agg[b + 8] = a0; agg[b + 9] = a1; agg[b + 10] = a2;
            agg[b + 11] = a3; agg[b + 12] = a4;
        }
    }
}

// ---- Node linear 1: h1, y2b, z2 ----------------------------------------
__global__ void fused1(const float* __restrict__ agg, const float* __restrict__ x,
                       const float* __restrict__ cntf,
                       const float* __restrict__ W1l, const float* __restrict__ b1,
                       const float* __restrict__ W1r, const float* __restrict__ W2l,
                       const float* __restrict__ W2r,
                       unsigned* __restrict__ y2b, float* __restrict__ z2) {
    __shared__ float sWl[208], sWr[208], sb[16], sA[128], sB[128];
    for (int i = threadIdx.x; i < 208; i += blockDim.x) { sWl[i] = W1l[i]; sWr[i] = W1r[i]; }
    for (int i = threadIdx.x; i < 128; i += blockDim.x) { sA[i] = W2l[i]; sB[i] = W2r[i]; }
    if (threadIdx.x < 16) sb[threadIdx.x] = b1[threadIdx.x];
    __syncthreads();
    int n = blockIdx.x * blockDim.x + threadIdx.x;
    if (n >= N_NODES) return;
    float inv = 1.0f / fmaxf(cntf[n], 1.0f);
    float a[13], xv[13];
#pragma unroll
    for (int i = 0; i < 13; i++) { a[i] = agg[n * 13 + i] * inv; xv[i] = x[n * 13 + i]; }
    float h[16];
#pragma unroll
    for (int o = 0; o < 16; o++) {
        float acc = sb[o];
#pragma unroll
        for (int i = 0; i < 13; i++) acc += a[i] * sWl[i * 16 + o] + xv[i] * sWr[i * 16 + o];
        h[o] = lrelu(acc);
    }
    float ya[8];
#pragma unroll
    for (int o2 = 0; o2 < 8; o2++) {
        float y = 0.0f, za = 0.0f;
#pragma unroll
        for (int o = 0; o < 16; o++) { y += h[o] * sA[o * 8 + o2]; za += h[o] * sB[o * 8 + o2]; }
        ya[o2] = y;
        z2[n * 8 + o2] = za;
    }
    uint4 out;
    out.x = pk(ya[0], ya[1]); out.y = pk(ya[2], ya[3]);
    out.z = pk(ya[4], ya[5]); out.w = pk(ya[6], ya[7]);
    *(uint4*)&y2b[(size_t)n * 4u] = out;
}

// ---- Layer-2 gather + fused epilogue: h2 (in z2), y3b ------------------
// Block 0 zeroes pool/gcnt (consumed by agg4pool_k, next kernel).
__global__ __launch_bounds__(256) void agg8f_k(const unsigned* __restrict__ y2b,
                                               const unsigned* __restrict__ binned,
                                               const int* __restrict__ offs,
                                               const float* __restrict__ cntf,
                                               const float* __restrict__ b2,
                                               const float* __restrict__ W3l,
                                               float* __restrict__ z2h2,
                                               unsigned* __restrict__ y3b,
                                               float* __restrict__ pool) {
    __shared__ float sb[8], sW3[32];
    if (blockIdx.x == 0) {
        for (int i = threadIdx.x; i < N_GRAPHS * 5; i += 256) pool[i] = 0.0f;
    }
    if (threadIdx.x < 8) sb[threadIdx.x] = b2[threadIdx.x];
    if (threadIdx.x < 32) sW3[threadIdx.x] = W3l[threadIdx.x];
    __syncthreads();
    int g = blockIdx.x * 256 + threadIdx.x;
    if (g >= N_NODES) return;
    int bin = g >> BINB, f = g & (WIN - 1);
    float a0 = 0, a1 = 0, a2 = 0, a3 = 0, a4 = 0, a5 = 0, a6 = 0, a7 = 0;
#pragma unroll
    for (int q = 0; q < 4; q++) {
        int sub = (bin << 2) | q;
        const int* o = offs + (size_t)sub * 513;
        int s = o[f], e = o[f + 1];
        const unsigned* bp = binned + (size_t)sub * CAPQ;
        int k = s;
        for (; k + 4 <= e; k += 4) {
            unsigned w0 = bp[k], w1 = bp[k + 1], w2 = bp[k + 2], w3 = bp[k + 3];
            uint4 v0 = *(const uint4*)&y2b[(size_t)(w0 & 0x3FFFFu) * 4u];
            uint4 v1 = *(const uint4*)&y2b[(size_t)(w1 & 0x3FFFFu) * 4u];
            uint4 v2 = *(const uint4*)&y2b[(size_t)(w2 & 0x3FFFFu) * 4u];
            uint4 v3 = *(const uint4*)&y2b[(size_t)(w3 & 0x3FFFFu) * 4u];
            a0 += blo(v0.x) + blo(v1.x) + blo(v2.x) + blo(v3.x);
            a1 += bhi(v0.x) + bhi(v1.x) + bhi(v2.x) + bhi(v3.x);
            a2 += blo(v0.y) + blo(v1.y) + blo(v2.y) + blo(v3.y);
            a3 += bhi(v0.y) + bhi(v1.y) + bhi(v2.y) + bhi(v3.y);
            a4 += blo(v0.z) + blo(v1.z) + blo(v2.z) + blo(v3.z);
            a5 += bhi(v0.z) + bhi(v1.z) + bhi(v2.z) + bhi(v3.z);
            a6 += blo(v0.w) + blo(v1.w) + blo(v2.w) + blo(v3.w);
            a7 += bhi(v0.w) + bhi(v1.w) + bhi(v2.w) + bhi(v3.w);
        }
        for (; k < e; k++) {
            uint4 v = *(const uint4*)&y2b[(size_t)(bp[k] & 0x3FFFFu) * 4u];
            a0 += blo(v.x); a1 += bhi(v.x); a2 += blo(v.y); a3 += bhi(v.y);
            a4 += blo(v.z); a5 += bhi(v.z); a6 += blo(v.w); a7 += bhi(v.w);
        }
    }
    float inv = 1.0f / fmaxf(cntf[g], 1.0f);
    float h2v[8];
    float s8[8] = {a0, a1, a2, a3, a4, a5, a6, a7};
#pragma unroll
    for (int j = 0; j < 8; j++) {
        float v = s8[j] * inv + sb[j] + z2h2[(size_t)g * 8 + j];
        h2v[j] = lrelu(v);
        z2h2[(size_t)g * 8 + j] = h2v[j];
    }
    float y[4];
#pragma unroll
    for (int k = 0; k < 4; k++) {
        float acc = 0.0f;
#pragma unroll
        for (int j = 0; j < 8; j++) acc += h2v[j] * sW3[j * 4 + k];
        y[k] = acc;
    }
    uint2 out;
    out.x = pk(y[0], y[1]); out.y = pk(y[2], y[3]);
    *(uint2*)&y3b[(size_t)g * 2u] = out;
}

// ---- Layer-3 gather + fused epilogue + pooling -------------------------
__global__ __launch_bounds__(256) void agg4pool_k(const unsigned* __restrict__ y3b,
                                                  const unsigned* __restrict__ binned,
                                                  const int* __restrict__ offs,
                                                  const float* __restrict__ cntf,
                                                  const float* __restrict__ h2,
                                                  const float* __restrict__ W3r,
                                                  const float* __restrict__ b3,
                                                  const int* __restrict__ batch,
                                                  float* __restrict__ pool,
                                                  float* __restrict__ gcnt) {
    __shared__ float sW[32], sb[4];
    __shared__ float lp[16][4];
    __shared__ float lc[16];
    __shared__ int sbase;
    if (threadIdx.x < 32) sW[threadIdx.x] = W3r[threadIdx.x];
    if (threadIdx.x < 4) sb[threadIdx.x] = b3[threadIdx.x];
    if (threadIdx.x < 16) {
        lc[threadIdx.x] = 0.0f;
        for (int k = 0; k < 4; k++) lp[threadIdx.x][k] = 0.0f;
    }
    int n0 = blockIdx.x * 256;
    if (threadIdx.x == 0) sbase = batch[n0 < N_NODES ? n0 : N_NODES - 1];
    __syncthreads();
    int g = n0 + threadIdx.x;
    if (g < N_NODES) {
        int bin = g >> BINB, f = g & (WIN - 1);
        float a0 = 0, a1 = 0, a2 = 0, a3 = 0;
#pragma unroll
        for (int q = 0; q < 4; q++) {
            int sub = (bin << 2) | q;
            const int* o = offs + (size_t)sub * 513;
            int s = o[f], e = o[f + 1];
            const unsigned* bp = binned + (size_t)sub * CAPQ;
            int k = s;
            for (; k + 4 <= e; k += 4) {
                unsigned w0 = bp[k], w1 = bp[k + 1], w2 = bp[k + 2], w3 = bp[k + 3];
                uint2 v0 = *(const uint2*)&y3b[(size_t)(w0 & 0x3FFFFu) * 2u];
                uint2 v1 = *(const uint2*)&y3b[(size_t)(w1 & 0x3FFFFu) * 2u];
                uint2 v2 = *(const uint2*)&y3b[(size_t)(w2 & 0x3FFFFu) * 2u];
                uint2 v3 = *(const uint2*)&y3b[(size_t)(w3 & 0x3FFFFu) * 2u];
                a0 += blo(v0.x) + blo(v1.x) + blo(v2.x) + blo(v3.x);
                a1 += bhi(v0.x) + bhi(v1.x) + bhi(v2.x) + bhi(v3.x);
                a2 += blo(v0.y) + blo(v1.y) + blo(v2.y) + blo(v3.y);
                a3 += bhi(v0.y) + bhi(v1.y) + bhi(v2.y) + bhi(v3.y);
            }
            for (; k < e; k++) {
                uint2 v = *(const uint2*)&y3b[(size_t)(bp[k] & 0x3FFFFu) * 2u];
                a0 += blo(v.x); a1 += bhi(v.x); a2 += blo(v.y); a3 += bhi(v.y);
            }
        }
        float inv = 1.0f / fmaxf(cntf[g], 1.0f);
        float s4[4] = {a0, a1, a2, a3};
        float h2v[8];
#pragma unroll
        for (int j = 0; j < 8; j++) h2v[j] = h2[(size_t)g * 8 + j];
        int b = batch[g];
        int off = b - sbase;
        bool local = (off >= 0 && off < 16);
#pragma unroll
        for (int k = 0; k < 4; k++) {
            float z = 0.0f;
#pragma unroll
            for (int j = 0; j < 8; j++) z += h2v[j] * sW[j * 4 + k];
            float v = s4[k] * inv + sb[k] + z;
            if (local) atomicAdd(&lp[off][k], v);
            else atomicAdd(&pool[b * 4 + k], v);
        }
        if (local) atomicAdd(&lc[off], 1.0f);
        else atomicAdd(&gcnt[b], 1.0f);
    }
    __syncthreads();
    if (threadIdx.x < 16) {
        int b = sbase + threadIdx.x;
        float c = lc[threadIdx.x];
        if (c > 0.0f && b < N_GRAPHS) {
            atomicAdd(&gcnt[b], c);
            for (int k = 0; k < 4; k++) atomicAdd(&pool[b * 4 + k], lp[threadIdx.x][k]);
        }
    }
}

__global__ void final_k(const float* __restrict__ pool, const float* __restrict__ gcnt,
                        const float* __restrict__ Wc, const float* __restrict__ bc,
                        float* __restrict__ out) {
    int g = blockIdx.x * blockDim.x + threadIdx.x;
    if (g >= N_GRAPHS) return;
    float inv = 1.0f / fmaxf(gcnt[g], 1.0f);
    float acc = bc[0];
#pragma unroll
    for (int k = 0; k < 4; k++) {
        float ap = pool[g * 4 + k];
        acc += ap * inv * Wc[k] + ap * Wc[4 + k];
    }
    out[g] = acc;
}

extern "C" void kernel_launch(void* const* d_in, const int* in_sizes, int n_in,
                              void* d_out, int out_size, void* d_ws, size_t ws_size,
                              hipStream_t stream) {
    const float* x = (const float*)d_in[0];
    const int* ei = (const int*)d_in[1];
    const int* src = ei;
    const int* dst = ei + N_EDGES;
    const int* batch = (const int*)d_in[2];
    const float* W1l = (const float*)d_in[3];
    const float* b1 = (const float*)d_in[4];
    const float* W1r = (const float*)d_in[5];
    const float* W2l = (const float*)d_in[6];
    const float* b2 = (const float*)d_in[7];
    const float* W2r = (const float*)d_in[8];
    const float* W3l = (const float*)d_in[9];
    const float* b3 = (const float*)d_in[10];
    const float* W3r = (const float*)d_in[11];
    const float* Wc = (const float*)d_in[12];
    const float* bc = (const float*)d_in[13];
    float* out = (float*)d_out;

    const size_t N = N_NODES;
    unsigned* binned = (unsigned*)d_ws;                 // NSUB*CAPQ u32 ~= 20 MB
    int* qcnt = (int*)(binned + (size_t)NSUB * CAPQ);   // 2048 ints
    int* offs = qcnt + 2048;                            // NSUB*513 ints ~= 4 MB
    float* fbase = (float*)(offs + (size_t)NSUB * 513);
    float* agg = fbase;                         // 13N floats
    float* cntf = fbase + 13 * N;               // N
    float* z2 = cntf + N;                       // 8N (becomes h2 in place)
    unsigned* x16b = (unsigned*)(z2 + 8 * N);   // 8N u32
    unsigned* y2b = x16b + 8 * N;               // 4N u32
    unsigned* y3b = y2b + 4 * N;                // 2N u32
    float* pool = (float*)(y3b + 2 * N);        // 2048 (gcnt follows)
    float* gcnt = pool + N_GRAPHS * 4;          // 512

    const int TPB = 256;
    const int NB = (N_NODES + TPB - 1) / TPB;

    // 7 dispatches total; zeroing folded into producers.
    pack_x<<<(N_NODES * 8 + TPB - 1) / TPB, TPB, 0, stream>>>(x, x16b, qcnt);
    partition_k<<<PART_BLOCKS, 1024, 0, stream>>>(src, dst, qcnt, binned);
    sortagg_k<<<NBINS, 1024, 0, stream>>>(x16b, binned, qcnt, offs, cntf, agg);
    fused1<<<NB, TPB, 0, stream>>>(agg, x, cntf, W1l, b1, W1r, W2l, W2r, y2b, z2);
    agg8f_k<<<NB, TPB, 0, stream>>>(y2b, binned, offs, cntf, b2, W3l, z2, y3b, pool);
    agg4pool_k<<<NB, TPB, 0, stream>>>(y3b, binned, offs, cntf, z2, W3r, b3, batch, pool, gcnt);
    final_k<<<2, TPB, 0, stream>>>(pool, gcnt, Wc, bc, out);
}